// Round 1
// baseline (2865.879 us; speedup 1.0000x reference)
//
#include <hip/hip_runtime.h>
#include <math.h>

// Problem constants
constexpr int B  = 8;
constexpr int N  = 1024;
constexpr int D  = 512;
constexpr int H  = 8;
constexpr int DH = 64;       // D / H
constexpr int M_ROWS = B * N; // 8192
constexpr float EPS_DIST = 1e-8f;
constexpr float EPS_LN   = 1e-5f;

// ---------------------------------------------------------------------------
// Block-wide sum over 256 threads (4 waves of 64). Caller provides red[8].
// ---------------------------------------------------------------------------
__device__ inline float block_sum256(float s, float* red) {
    for (int o = 32; o > 0; o >>= 1) s += __shfl_down(s, o, 64);
    int lane = threadIdx.x & 63, wid = threadIdx.x >> 6;
    if (lane == 0) red[wid] = s;
    __syncthreads();
    if (threadIdx.x == 0) red[4] = red[0] + red[1] + red[2] + red[3];
    __syncthreads();
    return red[4];
}

// ---------------------------------------------------------------------------
// LayerNorm over last dim (D=512). One block (256 thr) per row.
// If res != nullptr, normalizes (x + res).
// ---------------------------------------------------------------------------
__global__ __launch_bounds__(256) void ln_kernel(const float* __restrict__ x,
                                                 const float* __restrict__ res,
                                                 const float* __restrict__ gamma,
                                                 const float* __restrict__ beta,
                                                 float* __restrict__ out) {
    __shared__ float red[8];
    const int row = blockIdx.x;
    const int t = threadIdx.x;
    const float* xr = x + (size_t)row * D;

    float v0 = xr[t];
    float v1 = xr[t + 256];
    if (res) {
        const float* rr = res + (size_t)row * D;
        v0 += rr[t];
        v1 += rr[t + 256];
    }
    float mu = block_sum256(v0 + v1, red) * (1.0f / D);
    float d0 = v0 - mu, d1 = v1 - mu;
    float var = block_sum256(d0 * d0 + d1 * d1, red) * (1.0f / D);
    float rstd = rsqrtf(var + EPS_LN);
    out[(size_t)row * D + t]       = d0 * rstd * gamma[t]       + beta[t];
    out[(size_t)row * D + t + 256] = d1 * rstd * gamma[t + 256] + beta[t + 256];
}

// ---------------------------------------------------------------------------
// Tiled fp32 GEMM: C = A[M_ROWS,D] @ W[D,D] + bias.
// MODE 0: C row-major [M_ROWS, D]
// MODE 1: scatter to heads layout [B, H, N, DH]  (for Q/K/V)
// Block tile 64x64, 256 threads, 4x4 microtile, BK=16.
// ---------------------------------------------------------------------------
template <int MODE>
__global__ __launch_bounds__(256) void gemm_kernel(const float* __restrict__ A,
                                                   const float* __restrict__ W,
                                                   const float* __restrict__ bias,
                                                   float* __restrict__ C) {
    constexpr int BK = 16;
    __shared__ float As[BK][64 + 1];
    __shared__ float Ws[BK][64 + 1];

    const int col0 = blockIdx.x * 64;   // over D (8 blocks)
    const int row0 = blockIdx.y * 64;   // over M_ROWS (128 blocks)
    const int tid = threadIdx.x;
    const int tx = tid & 15, ty = tid >> 4;

    float acc[4][4] = {};

    for (int k0 = 0; k0 < D; k0 += BK) {
        // A tile: 64 rows x 16 k
        #pragma unroll
        for (int i = tid; i < 64 * BK; i += 256) {
            int m = i >> 4, kk = i & 15;
            As[kk][m] = A[(size_t)(row0 + m) * D + k0 + kk];
        }
        // W tile: 16 k x 64 cols
        #pragma unroll
        for (int i = tid; i < BK * 64; i += 256) {
            int kk = i >> 6, n = i & 63;
            Ws[kk][n] = W[(size_t)(k0 + kk) * D + col0 + n];
        }
        __syncthreads();
        #pragma unroll
        for (int kk = 0; kk < BK; ++kk) {
            float a[4], bb[4];
            #pragma unroll
            for (int i = 0; i < 4; ++i) a[i] = As[kk][ty * 4 + i];
            #pragma unroll
            for (int j = 0; j < 4; ++j) bb[j] = Ws[kk][tx * 4 + j];
            #pragma unroll
            for (int i = 0; i < 4; ++i)
                #pragma unroll
                for (int j = 0; j < 4; ++j) acc[i][j] += a[i] * bb[j];
        }
        __syncthreads();
    }

    #pragma unroll
    for (int i = 0; i < 4; ++i) {
        int r = row0 + ty * 4 + i;
        #pragma unroll
        for (int j = 0; j < 4; ++j) {
            int c = col0 + tx * 4 + j;
            float v = acc[i][j] + bias[c];
            if (MODE == 0) {
                C[(size_t)r * D + c] = v;
            } else {
                int b_ = r >> 10, n_ = r & (N - 1);
                int hh = c >> 6, dd = c & (DH - 1);
                C[(((size_t)(b_ * H + hh) * N) + n_) * DH + dd] = v;
            }
        }
    }
}

// ---------------------------------------------------------------------------
// Distance attention. Grid: (N/TQ, B*H). Block: 256 threads handles TQ=4
// query rows for one (b,h). Scores kept in LDS (never hit HBM).
//   dist = sqrt(sum_d (q-k)^2 + eps);  attn = softmax(-dist);  out = attn @ V
// Output written directly in [B, N, D] layout (heads re-interleaved).
// ---------------------------------------------------------------------------
constexpr int TQ = 4;
__global__ __launch_bounds__(256) void attn_kernel(const float* __restrict__ Q,
                                                   const float* __restrict__ K,
                                                   const float* __restrict__ V,
                                                   float* __restrict__ O) {
    __shared__ float qs[TQ][DH];
    __shared__ float sc[TQ][N];     // 16 KB
    __shared__ float rsum[TQ];

    const int bh = blockIdx.y;                 // 0..63
    const int q0 = blockIdx.x * TQ;
    const int b_ = bh / H, h_ = bh % H;
    const float* Qb = Q + (size_t)bh * N * DH;
    const float* Kb = K + (size_t)bh * N * DH;
    const float* Vb = V + (size_t)bh * N * DH;

    const int tid = threadIdx.x;

    // load Q tile into LDS
    for (int i = tid; i < TQ * DH; i += 256)
        qs[i / DH][i % DH] = Qb[(size_t)(q0 + i / DH) * DH + (i % DH)];
    __syncthreads();

    // pass 1: all TQ*N scores
    for (int p = tid; p < TQ * N; p += 256) {
        int qi = p >> 10;          // p / N
        int m  = p & (N - 1);      // p % N
        const float4* kr = (const float4*)(Kb + (size_t)m * DH);
        const float4* qr = (const float4*)(&qs[qi][0]);
        float d2 = 0.f;
        #pragma unroll
        for (int d4 = 0; d4 < DH / 4; ++d4) {
            float4 kv = kr[d4], qv = qr[d4];
            float dx = qv.x - kv.x, dy = qv.y - kv.y;
            float dz = qv.z - kv.z, dw = qv.w - kv.w;
            d2 += dx * dx + dy * dy + dz * dz + dw * dw;
        }
        sc[qi][m] = -sqrtf(d2 + EPS_DIST);
    }
    __syncthreads();

    // per-query softmax: wave w owns query row w
    {
        const int lane = tid & 63, w = tid >> 6;
        float mx = -1e30f;
        for (int m = lane; m < N; m += 64) mx = fmaxf(mx, sc[w][m]);
        for (int o = 32; o > 0; o >>= 1) mx = fmaxf(mx, __shfl_xor(mx, o, 64));
        float sum = 0.f;
        for (int m = lane; m < N; m += 64) {
            float e = __expf(sc[w][m] - mx);
            sc[w][m] = e;
            sum += e;
        }
        for (int o = 32; o > 0; o >>= 1) sum += __shfl_xor(sum, o, 64);
        if (lane == 0) rsum[w] = 1.0f / sum;
    }
    __syncthreads();

    // pass 2: out[qi][d] = sum_m p[m] * V[m][d]
    {
        const int qi = tid >> 6;        // /DH
        const int d  = tid & (DH - 1);
        float acc = 0.f;
        #pragma unroll 4
        for (int m = 0; m < N; ++m)
            acc += sc[qi][m] * Vb[(size_t)m * DH + d];
        acc *= rsum[qi];
        O[((size_t)(b_ * N + (q0 + qi)) * D) + h_ * DH + d] = acc;
    }
}

// ---------------------------------------------------------------------------
extern "C" void kernel_launch(void* const* d_in, const int* in_sizes, int n_in,
                              void* d_out, int out_size, void* d_ws, size_t ws_size,
                              hipStream_t stream) {
    // setup_inputs() dict order:
    const float* x     = (const float*)d_in[0];
    const float* Wq    = (const float*)d_in[1];
    const float* Wk    = (const float*)d_in[2];
    const float* Wv    = (const float*)d_in[3];
    const float* Wo    = (const float*)d_in[4];
    const float* bq    = (const float*)d_in[5];
    const float* bk    = (const float*)d_in[6];
    const float* bv    = (const float*)d_in[7];
    const float* bo    = (const float*)d_in[8];
    const float* ln1_g = (const float*)d_in[9];
    const float* ln1_b = (const float*)d_in[10];
    const float* ln2_g = (const float*)d_in[11];
    const float* ln2_b = (const float*)d_in[12];
    float* out = (float*)d_out;

    // Workspace layout (floats): h | Q | K | V | O   (h reused for proj out)
    const size_t SZ = (size_t)M_ROWS * D;  // 4M floats each
    float* h  = (float*)d_ws;
    float* Qd = h  + SZ;
    float* Kd = Qd + SZ;
    float* Vd = Kd + SZ;
    float* Od = Vd + SZ;
    float* Y0 = h;   // reuse after Q/K/V are built

    // 1) pre-norm
    ln_kernel<<<M_ROWS, 256, 0, stream>>>(x, nullptr, ln1_g, ln1_b, h);

    // 2-4) QKV projections (scatter into [B,H,N,DH])
    dim3 ggrid(D / 64, M_ROWS / 64);
    gemm_kernel<1><<<ggrid, 256, 0, stream>>>(h, Wq, bq, Qd);
    gemm_kernel<1><<<ggrid, 256, 0, stream>>>(h, Wk, bk, Kd);
    gemm_kernel<1><<<ggrid, 256, 0, stream>>>(h, Wv, bv, Vd);

    // 5) distance attention -> [B,N,D]
    attn_kernel<<<dim3(N / TQ, B * H), 256, 0, stream>>>(Qd, Kd, Vd, Od);

    // 6) output projection
    gemm_kernel<0><<<ggrid, 256, 0, stream>>>(Od, Wo, bo, Y0);

    // 7) residual + post-norm
    ln_kernel<<<M_ROWS, 256, 0, stream>>>(Y0, x, ln2_g, ln2_b, out);
}

// Round 2
// 248.223 us; speedup vs baseline: 11.5456x; 11.5456x over previous
//
#include <hip/hip_runtime.h>
#include <math.h>

typedef __attribute__((ext_vector_type(8))) short short8;   // 8 x bf16 (4 VGPRs)
typedef __attribute__((ext_vector_type(4))) float f32x4;    // MFMA acc

constexpr int B  = 8;
constexpr int N  = 1024;
constexpr int D  = 512;
constexpr int H  = 8;
constexpr int DH = 64;
constexpr int M_ROWS = 8192;
constexpr float EPS_DIST = 1e-8f;
constexpr float EPS_LN   = 1e-5f;

// fp32 -> bf16 bits (RNE)
__device__ inline unsigned short bfbits(float f) {
    union { float f; unsigned u; } v; v.f = f;
    unsigned r = v.u + 0x7fffu + ((v.u >> 16) & 1u);
    return (unsigned short)(r >> 16);
}
__device__ inline float bf2f(unsigned short s) {
    union { unsigned u; float f; } v; v.u = ((unsigned)s) << 16; return v.f;
}

// ---------------------------------------------------------------------------
// W [512k][512n] fp32  ->  Wt [512n][512k] bf16  (transpose + convert)
// thread handles a 4x4 tile: coalesced float4 reads, 8B ushort4 writes
// ---------------------------------------------------------------------------
__global__ __launch_bounds__(256) void wconv_kernel(const float* __restrict__ W,
                                                    unsigned short* __restrict__ Wt) {
    int t = blockIdx.x * 256 + threadIdx.x;      // 0..16383
    int tn = t & 127, tk = t >> 7;
    int k = tk * 4, n = tn * 4;
    float4 r0 = *(const float4*)&W[(size_t)(k + 0) * 512 + n];
    float4 r1 = *(const float4*)&W[(size_t)(k + 1) * 512 + n];
    float4 r2 = *(const float4*)&W[(size_t)(k + 2) * 512 + n];
    float4 r3 = *(const float4*)&W[(size_t)(k + 3) * 512 + n];
    ushort4 c;
    c.x = bfbits(r0.x); c.y = bfbits(r1.x); c.z = bfbits(r2.x); c.w = bfbits(r3.x);
    *(ushort4*)&Wt[(size_t)(n + 0) * 512 + k] = c;
    c.x = bfbits(r0.y); c.y = bfbits(r1.y); c.z = bfbits(r2.y); c.w = bfbits(r3.y);
    *(ushort4*)&Wt[(size_t)(n + 1) * 512 + k] = c;
    c.x = bfbits(r0.z); c.y = bfbits(r1.z); c.z = bfbits(r2.z); c.w = bfbits(r3.z);
    *(ushort4*)&Wt[(size_t)(n + 2) * 512 + k] = c;
    c.x = bfbits(r0.w); c.y = bfbits(r1.w); c.z = bfbits(r2.w); c.w = bfbits(r3.w);
    *(ushort4*)&Wt[(size_t)(n + 3) * 512 + k] = c;
}

// ---------------------------------------------------------------------------
// LayerNorm over D=512. One block per row. OUT_BF16: emit bf16 bits else fp32.
// If res != nullptr normalizes (x + res).
// ---------------------------------------------------------------------------
__device__ inline float block_sum256(float s, float* red) {
    for (int o = 32; o > 0; o >>= 1) s += __shfl_down(s, o, 64);
    int lane = threadIdx.x & 63, wid = threadIdx.x >> 6;
    if (lane == 0) red[wid] = s;
    __syncthreads();
    if (threadIdx.x == 0) red[4] = red[0] + red[1] + red[2] + red[3];
    __syncthreads();
    return red[4];
}

template <int OUT_BF16>
__global__ __launch_bounds__(256) void ln_kernel(const float* __restrict__ x,
                                                 const float* __restrict__ res,
                                                 const float* __restrict__ gamma,
                                                 const float* __restrict__ beta,
                                                 void* __restrict__ out) {
    __shared__ float red[8];
    const int row = blockIdx.x;
    const int t = threadIdx.x;
    const float* xr = x + (size_t)row * D;
    float v0 = xr[t], v1 = xr[t + 256];
    if (res) {
        const float* rr = res + (size_t)row * D;
        v0 += rr[t]; v1 += rr[t + 256];
    }
    float mu = block_sum256(v0 + v1, red) * (1.0f / D);
    float d0 = v0 - mu, d1 = v1 - mu;
    float var = block_sum256(d0 * d0 + d1 * d1, red) * (1.0f / D);
    float rstd = rsqrtf(var + EPS_LN);
    float o0 = d0 * rstd * gamma[t] + beta[t];
    float o1 = d1 * rstd * gamma[t + 256] + beta[t + 256];
    if (OUT_BF16) {
        ((unsigned short*)out)[(size_t)row * D + t]       = bfbits(o0);
        ((unsigned short*)out)[(size_t)row * D + t + 256] = bfbits(o1);
    } else {
        ((float*)out)[(size_t)row * D + t]       = o0;
        ((float*)out)[(size_t)row * D + t + 256] = o1;
    }
}

// ---------------------------------------------------------------------------
// bf16 MFMA GEMM: C = A[M,512]bf16 @ W[512,512] + bias, W given pre-transposed
// Wt[n][k]. Block tile 64x64, BK=32, 4 waves each 32x32 (2x2 MFMA tiles).
// MODE 0: fp32 row-major out. MODE 1: bf16 out scattered to [B,H,N,DH].
// ---------------------------------------------------------------------------
template <int MODE>
__global__ __launch_bounds__(256) void gemm_bf16(const unsigned short* __restrict__ A,
                                                 const unsigned short* __restrict__ Wt,
                                                 const float* __restrict__ bias,
                                                 void* __restrict__ Cout) {
    __shared__ unsigned short As[64][40];   // pad 40: 80B rows, 16B aligned
    __shared__ unsigned short Bs[64][40];
    const int col0 = blockIdx.x * 64;
    const int row0 = blockIdx.y * 64;
    const int tid = threadIdx.x;
    const int lane = tid & 63, w = tid >> 6;
    const int quad = lane >> 4, l15 = lane & 15;
    const int wm = (w & 1) * 32, wn = (w >> 1) * 32;

    f32x4 acc[2][2];
    #pragma unroll
    for (int i = 0; i < 2; ++i)
        #pragma unroll
        for (int j = 0; j < 2; ++j) acc[i][j] = (f32x4){0.f, 0.f, 0.f, 0.f};

    const int srow = tid >> 2;
    const int sk   = (tid & 3) * 8;
    for (int k0 = 0; k0 < 512; k0 += 32) {
        __syncthreads();
        *(uint4*)&As[srow][sk] = *(const uint4*)&A [(size_t)(row0 + srow) * 512 + k0 + sk];
        *(uint4*)&Bs[srow][sk] = *(const uint4*)&Wt[(size_t)(col0 + srow) * 512 + k0 + sk];
        __syncthreads();
        short8 af0 = *(const short8*)&As[wm + l15     ][quad * 8];
        short8 af1 = *(const short8*)&As[wm + 16 + l15][quad * 8];
        short8 bf0 = *(const short8*)&Bs[wn + l15     ][quad * 8];
        short8 bf1 = *(const short8*)&Bs[wn + 16 + l15][quad * 8];
        acc[0][0] = __builtin_amdgcn_mfma_f32_16x16x32_bf16(af0, bf0, acc[0][0], 0, 0, 0);
        acc[0][1] = __builtin_amdgcn_mfma_f32_16x16x32_bf16(af0, bf1, acc[0][1], 0, 0, 0);
        acc[1][0] = __builtin_amdgcn_mfma_f32_16x16x32_bf16(af1, bf0, acc[1][0], 0, 0, 0);
        acc[1][1] = __builtin_amdgcn_mfma_f32_16x16x32_bf16(af1, bf1, acc[1][1], 0, 0, 0);
    }

    #pragma unroll
    for (int mt = 0; mt < 2; ++mt)
        #pragma unroll
        for (int nt = 0; nt < 2; ++nt) {
            int col = col0 + wn + nt * 16 + l15;
            float bv = bias[col];
            #pragma unroll
            for (int r = 0; r < 4; ++r) {
                int row = row0 + wm + mt * 16 + quad * 4 + r;
                float v = acc[mt][nt][r] + bv;
                if (MODE == 0) {
                    ((float*)Cout)[(size_t)row * 512 + col] = v;
                } else {
                    int b_ = row >> 10, n_ = row & 1023;
                    int h_ = col >> 6,  dd = col & 63;
                    ((unsigned short*)Cout)[(((size_t)(b_ * H + h_) * N) + n_) * DH + dd] = bfbits(v);
                }
            }
        }
}

// ---------------------------------------------------------------------------
// Row sum-of-squares for Q and K (bf16 [64][1024][64] -> fp32 [65536]).
// 8 threads per row, fully coalesced.
// ---------------------------------------------------------------------------
__global__ __launch_bounds__(256) void sq_kernel(const unsigned short* __restrict__ Q,
                                                 const unsigned short* __restrict__ K,
                                                 float* __restrict__ qsq,
                                                 float* __restrict__ ksq) {
    int gid = blockIdx.x * 256 + threadIdx.x;    // 0 .. 1048575
    int row = gid >> 3;                          // 0 .. 131071
    int off = (gid & 7) * 8;
    int r = row & 65535;
    const unsigned short* p = ((row < 65536) ? Q : K) + (size_t)r * 64 + off;
    uint4 u = *(const uint4*)p;
    unsigned a[4] = {u.x, u.y, u.z, u.w};
    float s = 0.f;
    #pragma unroll
    for (int i = 0; i < 4; ++i) {
        float lo = bf2f((unsigned short)(a[i] & 0xffff));
        float hi = bf2f((unsigned short)(a[i] >> 16));
        s += lo * lo + hi * hi;
    }
    for (int m = 1; m < 8; m <<= 1) s += __shfl_xor(s, m, 64);
    if ((gid & 7) == 0) ((row < 65536) ? qsq : ksq)[r] = s;
}

// ---------------------------------------------------------------------------
// MFMA distance attention. Block = 4 waves = 64 query rows for one (b,h).
// 16 key-tiles of 64. S = Q.K^T (MFMA) -> d2 = q2+k2-2s -> p=exp(-dist)
// (no max-trick needed: -dist<=0) -> P through LDS -> PV (MFMA).
// ---------------------------------------------------------------------------
__global__ __launch_bounds__(256) void attn_kernel(const unsigned short* __restrict__ Q,
                                                   const unsigned short* __restrict__ K,
                                                   const unsigned short* __restrict__ V,
                                                   const float* __restrict__ qsq,
                                                   const float* __restrict__ ksq,
                                                   unsigned short* __restrict__ O) {
    __shared__ unsigned short Ks[64][72];      // [key][d]
    __shared__ unsigned short Vt[64][72];      // [d][key]  (transposed)
    __shared__ unsigned short Ps[4][16][72];   // per-wave P [q][key]
    __shared__ float ksq_s[64];

    const int bh = blockIdx.y;
    const int q0 = blockIdx.x * 64;
    const int tid = threadIdx.x;
    const int lane = tid & 63, w = tid >> 6;
    const int quad = lane >> 4, l15 = lane & 15;
    const int b_ = bh >> 3, h_ = bh & 7;

    const unsigned short* Qb = Q + (size_t)bh * N * DH;
    const unsigned short* Kb = K + (size_t)bh * N * DH;
    const unsigned short* Vb = V + (size_t)bh * N * DH;

    // Q fragments (A-layout): row = q0 + w*16 + l15, k = kc*32 + quad*8 + j
    short8 qf0, qf1;
    {
        const unsigned short* qp = Qb + (size_t)(q0 + w * 16 + l15) * 64 + quad * 8;
        qf0 = *(const short8*)qp;
        qf1 = *(const short8*)(qp + 32);
    }
    float qsq_l[4];
    #pragma unroll
    for (int r = 0; r < 4; ++r)
        qsq_l[r] = qsq[bh * N + q0 + w * 16 + quad * 4 + r];

    f32x4 oacc[4];
    #pragma unroll
    for (int dt = 0; dt < 4; ++dt) oacc[dt] = (f32x4){0.f, 0.f, 0.f, 0.f};
    float dpart[4] = {0.f, 0.f, 0.f, 0.f};

    for (int kt = 0; kt < 16; ++kt) {
        __syncthreads();
        // stage K tile [64 keys][64 d], row-major, coalesced
        {
            int key = tid >> 2, kd = (tid & 3) * 16;
            const unsigned short* kg = Kb + (size_t)(kt * 64 + key) * 64 + kd;
            *(uint4*)&Ks[key][kd]     = *(const uint4*)kg;
            *(uint4*)&Ks[key][kd + 8] = *(const uint4*)(kg + 8);
        }
        // stage V tile transposed: wave w covers d in [w*16, w*16+16), lane = key
        {
            #pragma unroll
            for (int g = 0; g < 2; ++g) {
                int d0_ = w * 16 + g * 8;
                uint4 u = *(const uint4*)&Vb[(size_t)(kt * 64 + lane) * 64 + d0_];
                unsigned a[4] = {u.x, u.y, u.z, u.w};
                #pragma unroll
                for (int j2 = 0; j2 < 4; ++j2) {
                    Vt[d0_ + j2 * 2    ][lane] = (unsigned short)(a[j2] & 0xffff);
                    Vt[d0_ + j2 * 2 + 1][lane] = (unsigned short)(a[j2] >> 16);
                }
            }
        }
        if (tid < 64) ksq_s[tid] = ksq[bh * N + kt * 64 + tid];
        __syncthreads();

        // S tiles + score transform + P to LDS
        #pragma unroll
        for (int kb = 0; kb < 4; ++kb) {
            short8 kf0 = *(const short8*)&Ks[kb * 16 + l15][quad * 8];
            short8 kf1 = *(const short8*)&Ks[kb * 16 + l15][32 + quad * 8];
            f32x4 sa = (f32x4){0.f, 0.f, 0.f, 0.f};
            sa = __builtin_amdgcn_mfma_f32_16x16x32_bf16(qf0, kf0, sa, 0, 0, 0);
            sa = __builtin_amdgcn_mfma_f32_16x16x32_bf16(qf1, kf1, sa, 0, 0, 0);
            float ks2 = ksq_s[kb * 16 + l15];
            #pragma unroll
            for (int r = 0; r < 4; ++r) {
                float d2 = qsq_l[r] + ks2 - 2.0f * sa[r];
                d2 = fmaxf(d2, 0.f) + EPS_DIST;
                float p = __expf(-sqrtf(d2));
                dpart[r] += p;
                Ps[w][quad * 4 + r][kb * 16 + l15] = bfbits(p);
            }
        }

        // PV: A = P (through LDS), B = V (transposed tile)
        #pragma unroll
        for (int kc = 0; kc < 2; ++kc) {
            short8 pf = *(const short8*)&Ps[w][l15][kc * 32 + quad * 8];
            #pragma unroll
            for (int dt = 0; dt < 4; ++dt) {
                short8 vf = *(const short8*)&Vt[dt * 16 + l15][kc * 32 + quad * 8];
                oacc[dt] = __builtin_amdgcn_mfma_f32_16x16x32_bf16(pf, vf, oacc[dt], 0, 0, 0);
            }
        }
    }

    // denominator: sum p over keys = in-lane (done) + across 16 lanes in quad
    #pragma unroll
    for (int r = 0; r < 4; ++r) {
        float s = dpart[r];
        s += __shfl_xor(s, 1, 64);
        s += __shfl_xor(s, 2, 64);
        s += __shfl_xor(s, 4, 64);
        s += __shfl_xor(s, 8, 64);
        dpart[r] = 1.0f / s;
    }

    // write O [B,N,D] bf16
    #pragma unroll
    for (int dt = 0; dt < 4; ++dt)
        #pragma unroll
        for (int r = 0; r < 4; ++r) {
            int n_ = q0 + w * 16 + quad * 4 + r;
            O[((size_t)(b_ * N + n_) * D) + h_ * DH + dt * 16 + l15] =
                bfbits(oacc[dt][r] * dpart[r]);
        }
}

// ---------------------------------------------------------------------------
extern "C" void kernel_launch(void* const* d_in, const int* in_sizes, int n_in,
                              void* d_out, int out_size, void* d_ws, size_t ws_size,
                              hipStream_t stream) {
    const float* x     = (const float*)d_in[0];
    const float* Wq    = (const float*)d_in[1];
    const float* Wk    = (const float*)d_in[2];
    const float* Wv    = (const float*)d_in[3];
    const float* Wo    = (const float*)d_in[4];
    const float* bq    = (const float*)d_in[5];
    const float* bk    = (const float*)d_in[6];
    const float* bv    = (const float*)d_in[7];
    const float* bo    = (const float*)d_in[8];
    const float* ln1_g = (const float*)d_in[9];
    const float* ln1_b = (const float*)d_in[10];
    const float* ln2_g = (const float*)d_in[11];
    const float* ln2_b = (const float*)d_in[12];
    float* out = (float*)d_out;

    // workspace layout
    unsigned short* WtQ  = (unsigned short*)d_ws;          // 512*512 bf16 each
    unsigned short* WtK  = WtQ + 262144;
    unsigned short* WtV  = WtK + 262144;
    unsigned short* WtO  = WtV + 262144;
    unsigned short* h_bf = WtO + 262144;                   // [8192,512] bf16
    unsigned short* Qb   = h_bf + 4194304;                 // [64][1024][64] bf16
    unsigned short* Kb   = Qb + 4194304;
    unsigned short* Vb   = Kb + 4194304;
    unsigned short* Ob   = Vb + 4194304;                   // [8192,512] bf16
    float* Y0  = (float*)(Ob + 4194304);                   // [8192,512] fp32
    float* qsq = Y0 + 4194304;                             // [65536]
    float* ksq = qsq + 65536;

    // 1) convert+transpose weights to bf16
    wconv_kernel<<<64, 256, 0, stream>>>(Wq, WtQ);
    wconv_kernel<<<64, 256, 0, stream>>>(Wk, WtK);
    wconv_kernel<<<64, 256, 0, stream>>>(Wv, WtV);
    wconv_kernel<<<64, 256, 0, stream>>>(Wo, WtO);

    // 2) pre-norm -> bf16
    ln_kernel<1><<<M_ROWS, 256, 0, stream>>>(x, nullptr, ln1_g, ln1_b, h_bf);

    // 3) QKV projections (bf16 MFMA, scatter to [B,H,N,DH])
    dim3 gg(D / 64, M_ROWS / 64);
    gemm_bf16<1><<<gg, 256, 0, stream>>>(h_bf, WtQ, bq, Qb);
    gemm_bf16<1><<<gg, 256, 0, stream>>>(h_bf, WtK, bk, Kb);
    gemm_bf16<1><<<gg, 256, 0, stream>>>(h_bf, WtV, bv, Vb);

    // 4) row sums of squares
    sq_kernel<<<4096, 256, 0, stream>>>(Qb, Kb, qsq, ksq);

    // 5) MFMA distance attention -> Ob [B,N,D] bf16
    attn_kernel<<<dim3(N / 64, B * H), 256, 0, stream>>>(Qb, Kb, Vb, qsq, ksq, Ob);

    // 6) output projection (fp32 out)
    gemm_bf16<0><<<gg, 256, 0, stream>>>(Ob, WtO, bo, Y0);

    // 7) residual + post-norm
    ln_kernel<0><<<M_ROWS, 256, 0, stream>>>(Y0, x, ln2_g, ln2_b, out);
}

// Round 3
// 207.944 us; speedup vs baseline: 13.7820x; 1.1937x over previous
//
#include <hip/hip_runtime.h>
#include <math.h>

typedef __attribute__((ext_vector_type(8))) short short8;   // 8 x bf16 (4 VGPRs)
typedef __attribute__((ext_vector_type(4))) float f32x4;    // MFMA acc

constexpr int B  = 8;
constexpr int N  = 1024;
constexpr int D  = 512;
constexpr int H  = 8;
constexpr int DH = 64;
constexpr int M_ROWS = 8192;
constexpr float EPS_DIST = 1e-8f;
constexpr float EPS_LN   = 1e-5f;

// fp32 -> bf16 bits (RNE)
__device__ inline unsigned short bfbits(float f) {
    union { float f; unsigned u; } v; v.f = f;
    unsigned r = v.u + 0x7fffu + ((v.u >> 16) & 1u);
    return (unsigned short)(r >> 16);
}
__device__ inline float bf2f(unsigned short s) {
    union { unsigned u; float f; } v; v.u = ((unsigned)s) << 16; return v.f;
}

// async 16B global->LDS (per lane; LDS dest must be wave-uniform base + lane*16)
__device__ inline void async_ld16(unsigned short* lds, const unsigned short* g) {
    __builtin_amdgcn_global_load_lds(
        (const __attribute__((address_space(1))) unsigned int*)(g),
        (__attribute__((address_space(3))) unsigned int*)(lds),
        16, 0, 0);
}

// ---------------------------------------------------------------------------
// All four weights [512k][512n] fp32 -> WtAll bf16 [4][512n][512k] (transpose)
// ---------------------------------------------------------------------------
__global__ __launch_bounds__(256) void wconv_kernel(const float* __restrict__ Wq,
                                                    const float* __restrict__ Wk,
                                                    const float* __restrict__ Wv,
                                                    const float* __restrict__ Wo,
                                                    unsigned short* __restrict__ WtAll) {
    int bx = blockIdx.x;
    int sub = bx >> 6;
    const float* W = sub == 0 ? Wq : sub == 1 ? Wk : sub == 2 ? Wv : Wo;
    unsigned short* Wt = WtAll + (size_t)sub * 262144;
    int t = (bx & 63) * 256 + threadIdx.x;       // 0..16383
    int tn = t & 127, tk = t >> 7;
    int k = tk * 4, n = tn * 4;
    float4 r0 = *(const float4*)&W[(size_t)(k + 0) * 512 + n];
    float4 r1 = *(const float4*)&W[(size_t)(k + 1) * 512 + n];
    float4 r2 = *(const float4*)&W[(size_t)(k + 2) * 512 + n];
    float4 r3 = *(const float4*)&W[(size_t)(k + 3) * 512 + n];
    ushort4 c;
    c.x = bfbits(r0.x); c.y = bfbits(r1.x); c.z = bfbits(r2.x); c.w = bfbits(r3.x);
    *(ushort4*)&Wt[(size_t)(n + 0) * 512 + k] = c;
    c.x = bfbits(r0.y); c.y = bfbits(r1.y); c.z = bfbits(r2.y); c.w = bfbits(r3.y);
    *(ushort4*)&Wt[(size_t)(n + 1) * 512 + k] = c;
    c.x = bfbits(r0.z); c.y = bfbits(r1.z); c.z = bfbits(r2.z); c.w = bfbits(r3.z);
    *(ushort4*)&Wt[(size_t)(n + 2) * 512 + k] = c;
    c.x = bfbits(r0.w); c.y = bfbits(r1.w); c.z = bfbits(r2.w); c.w = bfbits(r3.w);
    *(ushort4*)&Wt[(size_t)(n + 3) * 512 + k] = c;
}

// ---------------------------------------------------------------------------
// LayerNorm over D=512. One block per row.
// ---------------------------------------------------------------------------
__device__ inline float block_sum256(float s, float* red) {
    for (int o = 32; o > 0; o >>= 1) s += __shfl_down(s, o, 64);
    int lane = threadIdx.x & 63, wid = threadIdx.x >> 6;
    if (lane == 0) red[wid] = s;
    __syncthreads();
    if (threadIdx.x == 0) red[4] = red[0] + red[1] + red[2] + red[3];
    __syncthreads();
    return red[4];
}

template <int OUT_BF16>
__global__ __launch_bounds__(256) void ln_kernel(const float* __restrict__ x,
                                                 const float* __restrict__ res,
                                                 const float* __restrict__ gamma,
                                                 const float* __restrict__ beta,
                                                 void* __restrict__ out) {
    __shared__ float red[8];
    const int row = blockIdx.x;
    const int t = threadIdx.x;
    const float* xr = x + (size_t)row * D;
    float v0 = xr[t], v1 = xr[t + 256];
    if (res) {
        const float* rr = res + (size_t)row * D;
        v0 += rr[t]; v1 += rr[t + 256];
    }
    float mu = block_sum256(v0 + v1, red) * (1.0f / D);
    float d0 = v0 - mu, d1 = v1 - mu;
    float var = block_sum256(d0 * d0 + d1 * d1, red) * (1.0f / D);
    float rstd = rsqrtf(var + EPS_LN);
    float o0 = d0 * rstd * gamma[t] + beta[t];
    float o1 = d1 * rstd * gamma[t + 256] + beta[t + 256];
    if (OUT_BF16) {
        ((unsigned short*)out)[(size_t)row * D + t]       = bfbits(o0);
        ((unsigned short*)out)[(size_t)row * D + t + 256] = bfbits(o1);
    } else {
        ((float*)out)[(size_t)row * D + t]       = o0;
        ((float*)out)[(size_t)row * D + t + 256] = o1;
    }
}

// ---------------------------------------------------------------------------
// 128x128-tile bf16 MFMA GEMM (m97 structure), A[M,512] @ Wt[n][k].
// MODE 0: fp32 out row-major (out-proj).  bias0 = bo, o0 = Y0.
// MODE 1: fused QKV epilogue. N=1536. Per-wave 64-col quadrant lies entirely
//   in one of Q/K/V and one head. Q,K -> [bh][n][dh] bf16 + row sum-squares.
//   V -> transposed [bh][dh][n] bf16 (packed ushort4 stores).
// ---------------------------------------------------------------------------
template <int MODE>
__global__ __launch_bounds__(256) void gemm128(const unsigned short* __restrict__ A,
                                               const unsigned short* __restrict__ Wt,
                                               const float* __restrict__ bias0,
                                               const float* __restrict__ bias1,
                                               const float* __restrict__ bias2,
                                               void* __restrict__ o0,
                                               unsigned short* __restrict__ Ko,
                                               unsigned short* __restrict__ Vo,
                                               float* __restrict__ sq0,
                                               float* __restrict__ sq1) {
    __shared__ unsigned short As[128 * 32];   // unpadded: global_load_lds layout
    __shared__ unsigned short Bs[128 * 32];

    const int tid = threadIdx.x;
    const int lane = tid & 63, wv = tid >> 6;
    const int quad = lane >> 4, l15 = lane & 15;
    const int row0 = blockIdx.y * 128, col0 = blockIdx.x * 128;
    const int wm = (wv & 1) * 64, wn = (wv >> 1) * 64;

    f32x4 acc[4][4];
    #pragma unroll
    for (int i = 0; i < 4; ++i)
        #pragma unroll
        for (int j = 0; j < 4; ++j) acc[i][j] = (f32x4){0.f, 0.f, 0.f, 0.f};

    const unsigned short* Ag = A  + (size_t)row0 * 512;
    const unsigned short* Bg = Wt + (size_t)col0 * 512;

    for (int k0 = 0; k0 < 512; k0 += 32) {
        __syncthreads();
        #pragma unroll
        for (int c = 0; c < 2; ++c) {
            int fu = c * 2048 + tid * 8;      // ushort units; 16B per lane
            int r = fu >> 5, ko = fu & 31;
            async_ld16(As + fu, Ag + (size_t)r * 512 + k0 + ko);
            async_ld16(Bs + fu, Bg + (size_t)r * 512 + k0 + ko);
        }
        __syncthreads();

        short8 af[4], bf[4];
        #pragma unroll
        for (int i = 0; i < 4; ++i)
            af[i] = *(const short8*)&As[(wm + i * 16 + l15) * 32 + quad * 8];
        #pragma unroll
        for (int j = 0; j < 4; ++j)
            bf[j] = *(const short8*)&Bs[(wn + j * 16 + l15) * 32 + quad * 8];
        #pragma unroll
        for (int i = 0; i < 4; ++i)
            #pragma unroll
            for (int j = 0; j < 4; ++j)
                acc[i][j] = __builtin_amdgcn_mfma_f32_16x16x32_bf16(af[i], bf[j], acc[i][j], 0, 0, 0);
    }

    if (MODE == 0) {
        float* C = (float*)o0;
        #pragma unroll
        for (int i = 0; i < 4; ++i)
            #pragma unroll
            for (int j = 0; j < 4; ++j) {
                int col = col0 + wn + j * 16 + l15;
                float bv = bias0[col];
                #pragma unroll
                for (int r = 0; r < 4; ++r) {
                    int row = row0 + wm + i * 16 + quad * 4 + r;
                    C[(size_t)row * 512 + col] = acc[i][j][r] + bv;
                }
            }
    } else {
        const int colg = col0 + wn;                // multiple of 64
        const int seg = colg >> 9;                 // 0=Q 1=K 2=V
        const int hh = (colg & 511) >> 6;
        const float* bias = seg == 0 ? bias0 : seg == 1 ? bias1 : bias2;

        if (seg < 2) {
            unsigned short* dst = seg == 0 ? (unsigned short*)o0 : Ko;
            float* sq = seg == 0 ? sq0 : sq1;
            #pragma unroll
            for (int i = 0; i < 4; ++i) {
                const int m0 = row0 + wm + i * 16 + quad * 4;
                float ss[4] = {0.f, 0.f, 0.f, 0.f};
                #pragma unroll
                for (int j = 0; j < 4; ++j) {
                    float bvj = bias[hh * 64 + j * 16 + l15];
                    #pragma unroll
                    for (int r = 0; r < 4; ++r) {
                        float v = acc[i][j][r] + bvj;
                        unsigned short ub = bfbits(v);
                        float vr = bf2f(ub);
                        ss[r] += vr * vr;
                        int m = m0 + r;
                        int b_ = m >> 10, n_ = m & 1023;
                        dst[((size_t)((b_ * 8 + hh) * 1024) + n_) * 64 + j * 16 + l15] = ub;
                    }
                }
                #pragma unroll
                for (int r = 0; r < 4; ++r) {
                    float s = ss[r];
                    s += __shfl_xor(s, 1, 64);
                    s += __shfl_xor(s, 2, 64);
                    s += __shfl_xor(s, 4, 64);
                    s += __shfl_xor(s, 8, 64);
                    if (l15 == 0) {
                        int m = m0 + r;
                        sq[(size_t)((m >> 10) * 8 + hh) * 1024 + (m & 1023)] = s;
                    }
                }
            }
        } else {
            #pragma unroll
            for (int i = 0; i < 4; ++i) {
                const int m0 = row0 + wm + i * 16 + quad * 4;
                const int b_ = m0 >> 10, n_ = m0 & 1023;
                #pragma unroll
                for (int j = 0; j < 4; ++j) {
                    float bvj = bias[hh * 64 + j * 16 + l15];
                    ushort4 pk;
                    pk.x = bfbits(acc[i][j][0] + bvj);
                    pk.y = bfbits(acc[i][j][1] + bvj);
                    pk.z = bfbits(acc[i][j][2] + bvj);
                    pk.w = bfbits(acc[i][j][3] + bvj);
                    *(ushort4*)&Vo[((size_t)((b_ * 8 + hh) * 64) + j * 16 + l15) * 1024 + n_] = pk;
                }
            }
        }
    }
}

// ---------------------------------------------------------------------------
// MFMA distance attention. Block = 4 waves, 128 q rows (wave: 32 q) per (b,h).
// V pre-transposed in global [bh][dh][n]. 16 key-tiles of 64.
// ---------------------------------------------------------------------------
__global__ __launch_bounds__(256) void attn_kernel(const unsigned short* __restrict__ Q,
                                                   const unsigned short* __restrict__ K,
                                                   const unsigned short* __restrict__ Vt,
                                                   const float* __restrict__ qsq,
                                                   const float* __restrict__ ksq,
                                                   unsigned short* __restrict__ O) {
    __shared__ unsigned short Ks[64][72];      // [key][d]
    __shared__ unsigned short Vs[64][72];      // [d][key]
    __shared__ unsigned short Ps[4][32][72];   // per-wave P [q][key]
    __shared__ float ksq_s[64];

    const int bh = blockIdx.y;
    const int q0 = blockIdx.x * 128;
    const int tid = threadIdx.x;
    const int lane = tid & 63, w = tid >> 6;
    const int quad = lane >> 4, l15 = lane & 15;
    const int b_ = bh >> 3, h_ = bh & 7;

    const unsigned short* Qb = Q  + (size_t)bh * N * DH;
    const unsigned short* Kb = K  + (size_t)bh * N * DH;
    const unsigned short* Vb = Vt + (size_t)bh * DH * N;

    // Q fragments: rows q0 + w*32 + i*16 + l15
    short8 qf[2][2];
    #pragma unroll
    for (int i = 0; i < 2; ++i) {
        const unsigned short* qp = Qb + (size_t)(q0 + w * 32 + i * 16 + l15) * 64 + quad * 8;
        qf[i][0] = *(const short8*)qp;
        qf[i][1] = *(const short8*)(qp + 32);
    }
    float qe[2][4];
    #pragma unroll
    for (int i = 0; i < 2; ++i)
        #pragma unroll
        for (int r = 0; r < 4; ++r)
            qe[i][r] = qsq[bh * N + q0 + w * 32 + i * 16 + quad * 4 + r] + EPS_DIST;

    f32x4 oacc[2][4];
    #pragma unroll
    for (int i = 0; i < 2; ++i)
        #pragma unroll
        for (int dt = 0; dt < 4; ++dt) oacc[i][dt] = (f32x4){0.f, 0.f, 0.f, 0.f};
    float dpart[2][4] = {};

    for (int kt = 0; kt < 16; ++kt) {
        __syncthreads();
        {
            int rr = tid >> 2, c = (tid & 3) * 16;
            const unsigned short* kg = Kb + (size_t)(kt * 64 + rr) * 64 + c;
            *(uint4*)&Ks[rr][c]     = *(const uint4*)kg;
            *(uint4*)&Ks[rr][c + 8] = *(const uint4*)(kg + 8);
            const unsigned short* vg = Vb + (size_t)rr * N + kt * 64 + c;
            *(uint4*)&Vs[rr][c]     = *(const uint4*)vg;
            *(uint4*)&Vs[rr][c + 8] = *(const uint4*)(vg + 8);
        }
        if (tid < 64) ksq_s[tid] = ksq[bh * N + kt * 64 + tid];
        __syncthreads();

        // scores + transform -> Ps
        #pragma unroll
        for (int kb = 0; kb < 4; ++kb) {
            short8 kf0 = *(const short8*)&Ks[kb * 16 + l15][quad * 8];
            short8 kf1 = *(const short8*)&Ks[kb * 16 + l15][32 + quad * 8];
            float ks2 = ksq_s[kb * 16 + l15];
            #pragma unroll
            for (int i = 0; i < 2; ++i) {
                f32x4 sa = (f32x4){0.f, 0.f, 0.f, 0.f};
                sa = __builtin_amdgcn_mfma_f32_16x16x32_bf16(qf[i][0], kf0, sa, 0, 0, 0);
                sa = __builtin_amdgcn_mfma_f32_16x16x32_bf16(qf[i][1], kf1, sa, 0, 0, 0);
                #pragma unroll
                for (int r = 0; r < 4; ++r) {
                    float d2 = fmaf(-2.0f, sa[r], qe[i][r] + ks2);
                    d2 = fmaxf(d2, EPS_DIST);
                    float p = __expf(-__builtin_amdgcn_sqrtf(d2));
                    dpart[i][r] += p;
                    Ps[w][i * 16 + quad * 4 + r][kb * 16 + l15] = bfbits(p);
                }
            }
        }

        // PV
        short8 vf[4][2];
        #pragma unroll
        for (int dt = 0; dt < 4; ++dt)
            #pragma unroll
            for (int kc = 0; kc < 2; ++kc)
                vf[dt][kc] = *(const short8*)&Vs[dt * 16 + l15][kc * 32 + quad * 8];
        #pragma unroll
        for (int i = 0; i < 2; ++i)
            #pragma unroll
            for (int kc = 0; kc < 2; ++kc) {
                short8 pf = *(const short8*)&Ps[w][i * 16 + l15][kc * 32 + quad * 8];
                #pragma unroll
                for (int dt = 0; dt < 4; ++dt)
                    oacc[i][dt] = __builtin_amdgcn_mfma_f32_16x16x32_bf16(pf, vf[dt][kc], oacc[i][dt], 0, 0, 0);
            }
    }

    // denominators (reduce over the 16 l15 lanes in each quad)
    float rinv[2][4];
    #pragma unroll
    for (int i = 0; i < 2; ++i)
        #pragma unroll
        for (int r = 0; r < 4; ++r) {
            float s = dpart[i][r];
            s += __shfl_xor(s, 1, 64);
            s += __shfl_xor(s, 2, 64);
            s += __shfl_xor(s, 4, 64);
            s += __shfl_xor(s, 8, 64);
            rinv[i][r] = 1.0f / s;
        }

    #pragma unroll
    for (int i = 0; i < 2; ++i)
        #pragma unroll
        for (int dt = 0; dt < 4; ++dt)
            #pragma unroll
            for (int r = 0; r < 4; ++r) {
                int n_ = q0 + w * 32 + i * 16 + quad * 4 + r;
                O[((size_t)(b_ * N + n_) * D) + h_ * DH + dt * 16 + l15] =
                    bfbits(oacc[i][dt][r] * rinv[i][r]);
            }
}

// ---------------------------------------------------------------------------
extern "C" void kernel_launch(void* const* d_in, const int* in_sizes, int n_in,
                              void* d_out, int out_size, void* d_ws, size_t ws_size,
                              hipStream_t stream) {
    const float* x     = (const float*)d_in[0];
    const float* Wq    = (const float*)d_in[1];
    const float* Wk    = (const float*)d_in[2];
    const float* Wv    = (const float*)d_in[3];
    const float* Wo    = (const float*)d_in[4];
    const float* bq    = (const float*)d_in[5];
    const float* bk    = (const float*)d_in[6];
    const float* bv    = (const float*)d_in[7];
    const float* bo    = (const float*)d_in[8];
    const float* ln1_g = (const float*)d_in[9];
    const float* ln1_b = (const float*)d_in[10];
    const float* ln2_g = (const float*)d_in[11];
    const float* ln2_b = (const float*)d_in[12];
    float* out = (float*)d_out;

    // workspace (ushort units unless noted)
    unsigned short* WtAll = (unsigned short*)d_ws;    // [4][512][512] bf16
    unsigned short* h_bf  = WtAll + 4 * 262144;       // [8192][512]
    unsigned short* Qb    = h_bf + 4194304;           // [64][1024][64]
    unsigned short* Kb    = Qb + 4194304;
    unsigned short* Vtg   = Kb + 4194304;             // [64][64][1024] transposed
    unsigned short* Ob    = Vtg + 4194304;            // [8192][512]
    float* Y0  = (float*)(Ob + 4194304);              // [8192][512] fp32
    float* qsq = Y0 + 4194304;                        // [65536]
    float* ksq = qsq + 65536;

    // 1) weights -> bf16 transposed (Q|K|V|O concatenated)
    wconv_kernel<<<256, 256, 0, stream>>>(Wq, Wk, Wv, Wo, WtAll);

    // 2) pre-norm -> bf16
    ln_kernel<1><<<M_ROWS, 256, 0, stream>>>(x, nullptr, ln1_g, ln1_b, h_bf);

    // 3) fused QKV projection (N=1536) + scatter + sum-squares
    gemm128<1><<<dim3(12, 64), 256, 0, stream>>>(h_bf, WtAll, bq, bk, bv,
                                                 Qb, Kb, Vtg, qsq, ksq);

    // 4) MFMA distance attention -> Ob [B,N,D] bf16
    attn_kernel<<<dim3(8, 64), 256, 0, stream>>>(Qb, Kb, Vtg, qsq, ksq, Ob);

    // 5) output projection -> fp32
    gemm128<0><<<dim3(4, 64), 256, 0, stream>>>(Ob, WtAll + 3 * 262144, bo,
                                                nullptr, nullptr, Y0,
                                                nullptr, nullptr, nullptr, nullptr);

    // 6) residual + post-norm
    ln_kernel<0><<<M_ROWS, 256, 0, stream>>>(Y0, x, ln2_g, ln2_b, out);
}

// Round 4
// 188.743 us; speedup vs baseline: 15.1841x; 1.1017x over previous
//
#include <hip/hip_runtime.h>
#include <math.h>

typedef __attribute__((ext_vector_type(8))) short short8;   // 8 x bf16 (4 VGPRs)
typedef __attribute__((ext_vector_type(4))) float f32x4;    // MFMA acc

constexpr int B  = 8;
constexpr int N  = 1024;
constexpr int D  = 512;
constexpr int H  = 8;
constexpr int DH = 64;
constexpr int M_ROWS = 8192;
constexpr float EPS_DIST = 1e-8f;
constexpr float EPS_LN   = 1e-5f;

// fp32 -> bf16 bits (RNE)
__device__ inline unsigned short bfbits(float f) {
    union { float f; unsigned u; } v; v.f = f;
    unsigned r = v.u + 0x7fffu + ((v.u >> 16) & 1u);
    return (unsigned short)(r >> 16);
}
__device__ inline float bf2f(unsigned short s) {
    union { unsigned u; float f; } v; v.u = ((unsigned)s) << 16; return v.f;
}

// async 16B global->LDS (per lane; LDS dest = wave-uniform base + lane*16)
__device__ inline void async_ld16(unsigned short* lds, const unsigned short* g) {
    __builtin_amdgcn_global_load_lds(
        (const __attribute__((address_space(1))) unsigned int*)(g),
        (__attribute__((address_space(3))) unsigned int*)(lds),
        16, 0, 0);
}

// ---------------------------------------------------------------------------
// All four weights [512k][512n] fp32 -> WtAll bf16 [4][512n][512k] (transpose)
// ---------------------------------------------------------------------------
__global__ __launch_bounds__(256) void wconv_kernel(const float* __restrict__ Wq,
                                                    const float* __restrict__ Wk,
                                                    const float* __restrict__ Wv,
                                                    const float* __restrict__ Wo,
                                                    unsigned short* __restrict__ WtAll) {
    int bx = blockIdx.x;
    int sub = bx >> 6;
    const float* W = sub == 0 ? Wq : sub == 1 ? Wk : sub == 2 ? Wv : Wo;
    unsigned short* Wt = WtAll + (size_t)sub * 262144;
    int t = (bx & 63) * 256 + threadIdx.x;       // 0..16383
    int tn = t & 127, tk = t >> 7;
    int k = tk * 4, n = tn * 4;
    float4 r0 = *(const float4*)&W[(size_t)(k + 0) * 512 + n];
    float4 r1 = *(const float4*)&W[(size_t)(k + 1) * 512 + n];
    float4 r2 = *(const float4*)&W[(size_t)(k + 2) * 512 + n];
    float4 r3 = *(const float4*)&W[(size_t)(k + 3) * 512 + n];
    ushort4 c;
    c.x = bfbits(r0.x); c.y = bfbits(r1.x); c.z = bfbits(r2.x); c.w = bfbits(r3.x);
    *(ushort4*)&Wt[(size_t)(n + 0) * 512 + k] = c;
    c.x = bfbits(r0.y); c.y = bfbits(r1.y); c.z = bfbits(r2.y); c.w = bfbits(r3.y);
    *(ushort4*)&Wt[(size_t)(n + 1) * 512 + k] = c;
    c.x = bfbits(r0.z); c.y = bfbits(r1.z); c.z = bfbits(r2.z); c.w = bfbits(r3.z);
    *(ushort4*)&Wt[(size_t)(n + 2) * 512 + k] = c;
    c.x = bfbits(r0.w); c.y = bfbits(r1.w); c.z = bfbits(r2.w); c.w = bfbits(r3.w);
    *(ushort4*)&Wt[(size_t)(n + 3) * 512 + k] = c;
}

// ---------------------------------------------------------------------------
// LayerNorm over D=512. One block per row. Optional bf16 input / output.
// If res != nullptr normalizes (x + res), res always fp32.
// ---------------------------------------------------------------------------
__device__ inline float block_sum256(float s, float* red) {
    for (int o = 32; o > 0; o >>= 1) s += __shfl_down(s, o, 64);
    int lane = threadIdx.x & 63, wid = threadIdx.x >> 6;
    if (lane == 0) red[wid] = s;
    __syncthreads();
    if (threadIdx.x == 0) red[4] = red[0] + red[1] + red[2] + red[3];
    __syncthreads();
    return red[4];
}

template <int OUT_BF16, int IN_BF16>
__global__ __launch_bounds__(256) void ln_kernel(const void* __restrict__ xv,
                                                 const float* __restrict__ res,
                                                 const float* __restrict__ gamma,
                                                 const float* __restrict__ beta,
                                                 void* __restrict__ out) {
    __shared__ float red[8];
    const int row = blockIdx.x;
    const int t = threadIdx.x;
    float v0, v1;
    if (IN_BF16) {
        const unsigned short* xr = (const unsigned short*)xv + (size_t)row * D;
        v0 = bf2f(xr[t]); v1 = bf2f(xr[t + 256]);
    } else {
        const float* xr = (const float*)xv + (size_t)row * D;
        v0 = xr[t]; v1 = xr[t + 256];
    }
    if (res) {
        const float* rr = res + (size_t)row * D;
        v0 += rr[t]; v1 += rr[t + 256];
    }
    float mu = block_sum256(v0 + v1, red) * (1.0f / D);
    float d0 = v0 - mu, d1 = v1 - mu;
    float var = block_sum256(d0 * d0 + d1 * d1, red) * (1.0f / D);
    float rstd = rsqrtf(var + EPS_LN);
    float o0 = d0 * rstd * gamma[t] + beta[t];
    float o1 = d1 * rstd * gamma[t + 256] + beta[t + 256];
    if (OUT_BF16) {
        ((unsigned short*)out)[(size_t)row * D + t]       = bfbits(o0);
        ((unsigned short*)out)[(size_t)row * D + t + 256] = bfbits(o1);
    } else {
        ((float*)out)[(size_t)row * D + t]       = o0;
        ((float*)out)[(size_t)row * D + t + 256] = o1;
    }
}

// ---------------------------------------------------------------------------
// MTxnn-tile bf16 MFMA GEMM, A[M,512] @ Wt[n][k]. 1D grid, XCD-swizzled:
// by = id & (RB-1) so same-A-tile blocks share an XCD.
// MODE 0 (MT=64): bf16 out row-major (out-proj).
// MODE 1 (MT=128): fused QKV epilogue, N=1536. Q,K -> [bh][n][dh] + sumsq.
//   V -> [bh][dh][n] via LDS transpose (coalesced 128B stores).
// ---------------------------------------------------------------------------
template <int MODE, int MT>
__global__ __launch_bounds__(256) void gemm128(const unsigned short* __restrict__ A,
                                               const unsigned short* __restrict__ Wt,
                                               const float* __restrict__ bias0,
                                               const float* __restrict__ bias1,
                                               const float* __restrict__ bias2,
                                               void* __restrict__ o0,
                                               unsigned short* __restrict__ Ko,
                                               unsigned short* __restrict__ Vo,
                                               float* __restrict__ sq0,
                                               float* __restrict__ sq1) {
    constexpr int RB = M_ROWS / MT;            // row blocks: 64 (MT=128) / 128 (MT=64)
    constexpr int NI = MT / 32;                // acc row-tiles per wave
    constexpr int SMSZ = (MODE == 1) ? 18432 : (MT * 32 + 4096);
    __shared__ unsigned short smem[SMSZ];
    unsigned short* As = smem;                 // MT*32
    unsigned short* Bs = smem + MT * 32;       // 128*32

    const int id = blockIdx.x;
    const int by = id & (RB - 1), bx = id / RB;
    const int tid = threadIdx.x;
    const int lane = tid & 63, wv = tid >> 6;
    const int quad = lane >> 4, l15 = lane & 15;
    const int row0 = by * MT, col0 = bx * 128;
    const int wm = (wv & 1) * (MT / 2), wn = (wv >> 1) * 64;

    f32x4 acc[NI][4];
    #pragma unroll
    for (int i = 0; i < NI; ++i)
        #pragma unroll
        for (int j = 0; j < 4; ++j) acc[i][j] = (f32x4){0.f, 0.f, 0.f, 0.f};

    const unsigned short* Ag = A  + (size_t)row0 * 512;
    const unsigned short* Bg = Wt + (size_t)col0 * 512;

    for (int k0 = 0; k0 < 512; k0 += 32) {
        __syncthreads();
        #pragma unroll
        for (int c = 0; c < MT * 32 / 2048; ++c) {
            int fu = c * 2048 + tid * 8;
            int r = fu >> 5, ko = fu & 31;
            async_ld16(As + fu, Ag + (size_t)r * 512 + k0 + ko);
        }
        #pragma unroll
        for (int c = 0; c < 2; ++c) {
            int fu = c * 2048 + tid * 8;
            int r = fu >> 5, ko = fu & 31;
            async_ld16(Bs + fu, Bg + (size_t)r * 512 + k0 + ko);
        }
        __syncthreads();

        short8 af[NI], bf[4];
        #pragma unroll
        for (int i = 0; i < NI; ++i)
            af[i] = *(const short8*)&As[(wm + i * 16 + l15) * 32 + quad * 8];
        #pragma unroll
        for (int j = 0; j < 4; ++j)
            bf[j] = *(const short8*)&Bs[(wn + j * 16 + l15) * 32 + quad * 8];
        #pragma unroll
        for (int i = 0; i < NI; ++i)
            #pragma unroll
            for (int j = 0; j < 4; ++j)
                acc[i][j] = __builtin_amdgcn_mfma_f32_16x16x32_bf16(af[i], bf[j], acc[i][j], 0, 0, 0);
    }

    if (MODE == 0) {
        unsigned short* C = (unsigned short*)o0;
        #pragma unroll
        for (int i = 0; i < NI; ++i)
            #pragma unroll
            for (int j = 0; j < 4; ++j) {
                int col = col0 + wn + j * 16 + l15;
                float bv = bias0[col];
                #pragma unroll
                for (int r = 0; r < 4; ++r) {
                    int row = row0 + wm + i * 16 + quad * 4 + r;
                    C[(size_t)row * 512 + col] = bfbits(acc[i][j][r] + bv);
                }
            }
    } else {
        const int colg = col0 + wn;                // multiple of 64
        const int seg = colg >> 9;                 // 0=Q 1=K 2=V
        const int hh = (colg & 511) >> 6;
        const float* bias = seg == 0 ? bias0 : seg == 1 ? bias1 : bias2;

        if (seg < 2) {
            unsigned short* dst = seg == 0 ? (unsigned short*)o0 : Ko;
            float* sq = seg == 0 ? sq0 : sq1;
            #pragma unroll
            for (int i = 0; i < NI; ++i) {
                const int m0 = row0 + wm + i * 16 + quad * 4;
                float ss[4] = {0.f, 0.f, 0.f, 0.f};
                #pragma unroll
                for (int j = 0; j < 4; ++j) {
                    float bvj = bias[hh * 64 + j * 16 + l15];
                    #pragma unroll
                    for (int r = 0; r < 4; ++r) {
                        float v = acc[i][j][r] + bvj;
                        unsigned short ub = bfbits(v);
                        float vr = bf2f(ub);
                        ss[r] += vr * vr;
                        int m = m0 + r;
                        int b_ = m >> 10, n_ = m & 1023;
                        dst[((size_t)((b_ * 8 + hh) * 1024) + n_) * 64 + j * 16 + l15] = ub;
                    }
                }
                #pragma unroll
                for (int r = 0; r < 4; ++r) {
                    float s = ss[r];
                    s += __shfl_xor(s, 1, 64);
                    s += __shfl_xor(s, 2, 64);
                    s += __shfl_xor(s, 4, 64);
                    s += __shfl_xor(s, 8, 64);
                    if (l15 == 0) {
                        int m = m0 + r;
                        sq[(size_t)((m >> 10) * 8 + hh) * 1024 + (m & 1023)] = s;
                    }
                }
            }
        } else {
            // V: transpose through per-wave LDS region, then coalesced stores
            __syncthreads();                       // As/Bs done (all waves in this block are V)
            unsigned short* T = smem + wv * 4608;  // [64 d][72]
            #pragma unroll
            for (int i = 0; i < NI; ++i)
                #pragma unroll
                for (int j = 0; j < 4; ++j) {
                    float bvj = bias[hh * 64 + j * 16 + l15];
                    ushort4 pk;
                    pk.x = bfbits(acc[i][j][0] + bvj);
                    pk.y = bfbits(acc[i][j][1] + bvj);
                    pk.z = bfbits(acc[i][j][2] + bvj);
                    pk.w = bfbits(acc[i][j][3] + bvj);
                    // local d = j*16+l15, local n = i*16 + quad*4 + r
                    *(ushort4*)&T[(j * 16 + l15) * 72 + i * 16 + quad * 4] = pk;
                }
            const int b_ = (row0 + wm) >> 10;
            const int nbase = (row0 + wm) & 1023;
            unsigned short* Vg = Vo + ((size_t)((b_ * 8 + hh) * 64)) * 1024 + nbase;
            #pragma unroll
            for (int it = 0; it < 8; ++it) {
                int dl = it * 8 + (lane >> 3);
                int nl = (lane & 7) * 8;
                uint4 v = *(const uint4*)&T[dl * 72 + nl];
                *(uint4*)&Vg[(size_t)dl * 1024 + nl] = v;
            }
        }
    }
}

// ---------------------------------------------------------------------------
// MFMA distance attention. Block = 4 waves, 128 q rows (wave: 32 q) per (b,h).
// V pre-transposed [bh][dh][n]. Double-buffered K/V LDS + register prefetch:
// one barrier per key-tile. 1D grid, bh = id&63 so same-head blocks share XCD.
// ---------------------------------------------------------------------------
__global__ __launch_bounds__(256) void attn_kernel(const unsigned short* __restrict__ Q,
                                                   const unsigned short* __restrict__ K,
                                                   const unsigned short* __restrict__ Vt,
                                                   const float* __restrict__ qsq,
                                                   const float* __restrict__ ksq,
                                                   unsigned short* __restrict__ O) {
    __shared__ unsigned short Ks[2][64][72];
    __shared__ unsigned short Vs[2][64][72];
    __shared__ unsigned short Ps[4][32][72];
    __shared__ float ksq_s[2][64];

    const int id = blockIdx.x;
    const int bh = id & 63, qb = id >> 6;
    const int q0 = qb * 128;
    const int tid = threadIdx.x;
    const int lane = tid & 63, w = tid >> 6;
    const int quad = lane >> 4, l15 = lane & 15;
    const int b_ = bh >> 3, h_ = bh & 7;

    const unsigned short* Qb = Q  + (size_t)bh * N * DH;
    const unsigned short* Kb = K  + (size_t)bh * N * DH;
    const unsigned short* Vb = Vt + (size_t)bh * DH * N;

    // Q fragments: rows q0 + w*32 + i*16 + l15
    short8 qf[2][2];
    #pragma unroll
    for (int i = 0; i < 2; ++i) {
        const unsigned short* qp = Qb + (size_t)(q0 + w * 32 + i * 16 + l15) * 64 + quad * 8;
        qf[i][0] = *(const short8*)qp;
        qf[i][1] = *(const short8*)(qp + 32);
    }
    float qe[2][4];
    #pragma unroll
    for (int i = 0; i < 2; ++i)
        #pragma unroll
        for (int r = 0; r < 4; ++r)
            qe[i][r] = qsq[bh * N + q0 + w * 32 + i * 16 + quad * 4 + r] + EPS_DIST;

    f32x4 oacc[2][4];
    #pragma unroll
    for (int i = 0; i < 2; ++i)
        #pragma unroll
        for (int dt = 0; dt < 4; ++dt) oacc[i][dt] = (f32x4){0.f, 0.f, 0.f, 0.f};
    float dpart[2][4] = {};

    // staging registers
    const int rr = tid >> 2, cc = (tid & 3) * 16;
    uint4 kreg0, kreg1, vreg0, vreg1;
    float ksreg = 0.f;

    // prefetch tile 0
    {
        const unsigned short* kg = Kb + (size_t)rr * 64 + cc;
        kreg0 = *(const uint4*)kg; kreg1 = *(const uint4*)(kg + 8);
        const unsigned short* vg = Vb + (size_t)rr * N + cc;
        vreg0 = *(const uint4*)vg; vreg1 = *(const uint4*)(vg + 8);
        if (tid < 64) ksreg = ksq[bh * N + tid];
    }
    // store tile 0 -> buf 0
    *(uint4*)&Ks[0][rr][cc]     = kreg0;
    *(uint4*)&Ks[0][rr][cc + 8] = kreg1;
    *(uint4*)&Vs[0][rr][cc]     = vreg0;
    *(uint4*)&Vs[0][rr][cc + 8] = vreg1;
    if (tid < 64) ksq_s[0][tid] = ksreg;
    __syncthreads();

    for (int kt = 0; kt < 16; ++kt) {
        const int cur = kt & 1;
        if (kt < 15) {   // prefetch next tile into registers (latency hidden by compute)
            const unsigned short* kg = Kb + (size_t)((kt + 1) * 64 + rr) * 64 + cc;
            kreg0 = *(const uint4*)kg; kreg1 = *(const uint4*)(kg + 8);
            const unsigned short* vg = Vb + (size_t)rr * N + (kt + 1) * 64 + cc;
            vreg0 = *(const uint4*)vg; vreg1 = *(const uint4*)(vg + 8);
            if (tid < 64) ksreg = ksq[bh * N + (kt + 1) * 64 + tid];
        }

        // scores + transform -> Ps
        #pragma unroll
        for (int kb = 0; kb < 4; ++kb) {
            short8 kf0 = *(const short8*)&Ks[cur][kb * 16 + l15][quad * 8];
            short8 kf1 = *(const short8*)&Ks[cur][kb * 16 + l15][32 + quad * 8];
            float ks2 = ksq_s[cur][kb * 16 + l15];
            #pragma unroll
            for (int i = 0; i < 2; ++i) {
                f32x4 sa = (f32x4){0.f, 0.f, 0.f, 0.f};
                sa = __builtin_amdgcn_mfma_f32_16x16x32_bf16(qf[i][0], kf0, sa, 0, 0, 0);
                sa = __builtin_amdgcn_mfma_f32_16x16x32_bf16(qf[i][1], kf1, sa, 0, 0, 0);
                #pragma unroll
                for (int r = 0; r < 4; ++r) {
                    float d2 = fmaf(-2.0f, sa[r], qe[i][r] + ks2);
                    d2 = fmaxf(d2, EPS_DIST);
                    float p = __expf(-__builtin_amdgcn_sqrtf(d2));
                    dpart[i][r] += p;
                    Ps[w][i * 16 + quad * 4 + r][kb * 16 + l15] = bfbits(p);
                }
            }
        }

        // PV
        short8 vf[4][2];
        #pragma unroll
        for (int dt = 0; dt < 4; ++dt)
            #pragma unroll
            for (int kc = 0; kc < 2; ++kc)
                vf[dt][kc] = *(const short8*)&Vs[cur][dt * 16 + l15][kc * 32 + quad * 8];
        #pragma unroll
        for (int i = 0; i < 2; ++i)
            #pragma unroll
            for (int kc = 0; kc < 2; ++kc) {
                short8 pf = *(const short8*)&Ps[w][i * 16 + l15][kc * 32 + quad * 8];
                #pragma unroll
                for (int dt = 0; dt < 4; ++dt)
                    oacc[i][dt] = __builtin_amdgcn_mfma_f32_16x16x32_bf16(pf, vf[dt][kc], oacc[i][dt], 0, 0, 0);
            }

        if (kt < 15) {   // write prefetched tile into other buffer
            *(uint4*)&Ks[cur ^ 1][rr][cc]     = kreg0;
            *(uint4*)&Ks[cur ^ 1][rr][cc + 8] = kreg1;
            *(uint4*)&Vs[cur ^ 1][rr][cc]     = vreg0;
            *(uint4*)&Vs[cur ^ 1][rr][cc + 8] = vreg1;
            if (tid < 64) ksq_s[cur ^ 1][tid] = ksreg;
        }
        __syncthreads();
    }

    // denominators (reduce over the 16 l15 lanes in each quad)
    float rinv[2][4];
    #pragma unroll
    for (int i = 0; i < 2; ++i)
        #pragma unroll
        for (int r = 0; r < 4; ++r) {
            float s = dpart[i][r];
            s += __shfl_xor(s, 1, 64);
            s += __shfl_xor(s, 2, 64);
            s += __shfl_xor(s, 4, 64);
            s += __shfl_xor(s, 8, 64);
            rinv[i][r] = 1.0f / s;
        }

    #pragma unroll
    for (int i = 0; i < 2; ++i)
        #pragma unroll
        for (int dt = 0; dt < 4; ++dt)
            #pragma unroll
            for (int r = 0; r < 4; ++r) {
                int n_ = q0 + w * 32 + i * 16 + quad * 4 + r;
                O[((size_t)(b_ * N + n_) * D) + h_ * DH + dt * 16 + l15] =
                    bfbits(oacc[i][dt][r] * rinv[i][r]);
            }
}

// ---------------------------------------------------------------------------
extern "C" void kernel_launch(void* const* d_in, const int* in_sizes, int n_in,
                              void* d_out, int out_size, void* d_ws, size_t ws_size,
                              hipStream_t stream) {
    const float* x     = (const float*)d_in[0];
    const float* Wq    = (const float*)d_in[1];
    const float* Wk    = (const float*)d_in[2];
    const float* Wv    = (const float*)d_in[3];
    const float* Wo    = (const float*)d_in[4];
    const float* bq    = (const float*)d_in[5];
    const float* bk    = (const float*)d_in[6];
    const float* bv    = (const float*)d_in[7];
    const float* bo    = (const float*)d_in[8];
    const float* ln1_g = (const float*)d_in[9];
    const float* ln1_b = (const float*)d_in[10];
    const float* ln2_g = (const float*)d_in[11];
    const float* ln2_b = (const float*)d_in[12];
    float* out = (float*)d_out;

    // workspace (ushort units unless noted)
    unsigned short* WtAll = (unsigned short*)d_ws;    // [4][512][512] bf16
    unsigned short* h_bf  = WtAll + 4 * 262144;       // [8192][512]
    unsigned short* Qb    = h_bf + 4194304;           // [64][1024][64]
    unsigned short* Kb    = Qb + 4194304;
    unsigned short* Vtg   = Kb + 4194304;             // [64][64][1024] transposed
    unsigned short* Ob    = Vtg + 4194304;            // [8192][512]
    unsigned short* Y0    = Ob + 4194304;             // [8192][512] bf16
    float* qsq = (float*)(Y0 + 4194304);              // [65536]
    float* ksq = qsq + 65536;

    // 1) weights -> bf16 transposed (Q|K|V|O concatenated)
    wconv_kernel<<<256, 256, 0, stream>>>(Wq, Wk, Wv, Wo, WtAll);

    // 2) pre-norm -> bf16
    ln_kernel<1, 0><<<M_ROWS, 256, 0, stream>>>(x, nullptr, ln1_g, ln1_b, h_bf);

    // 3) fused QKV projection (N=1536) + scatter + sum-squares; XCD-swizzled 1D grid
    gemm128<1, 128><<<768, 256, 0, stream>>>(h_bf, WtAll, bq, bk, bv,
                                             Qb, Kb, Vtg, qsq, ksq);

    // 4) MFMA distance attention -> Ob [B,N,D] bf16
    attn_kernel<<<512, 256, 0, stream>>>(Qb, Kb, Vtg, qsq, ksq, Ob);

    // 5) output projection -> bf16 Y0
    gemm128<0, 64><<<512, 256, 0, stream>>>(Ob, WtAll + 3 * 262144, bo,
                                            nullptr, nullptr, Y0,
                                            nullptr, nullptr, nullptr, nullptr);

    // 6) residual + post-norm (bf16 Y0 + fp32 x) -> fp32 out
    ln_kernel<0, 1><<<M_ROWS, 256, 0, stream>>>(Y0, x, ln2_g, ln2_b, out);
}

// Round 5
// 182.807 us; speedup vs baseline: 15.6771x; 1.0325x over previous
//
#include <hip/hip_runtime.h>
#include <math.h>

typedef __attribute__((ext_vector_type(8))) short short8;   // 8 x bf16 (4 VGPRs)
typedef __attribute__((ext_vector_type(4))) float f32x4;    // MFMA acc

constexpr int B  = 8;
constexpr int N  = 1024;
constexpr int D  = 512;
constexpr int H  = 8;
constexpr int DH = 64;
constexpr int M_ROWS = 8192;
constexpr float EPS_DIST = 1e-8f;
constexpr float EPS_LN   = 1e-5f;

// fp32 -> bf16 bits (RNE)
__device__ inline unsigned short bfbits(float f) {
    union { float f; unsigned u; } v; v.f = f;
    unsigned r = v.u + 0x7fffu + ((v.u >> 16) & 1u);
    return (unsigned short)(r >> 16);
}
__device__ inline float bf2f(unsigned short s) {
    union { unsigned u; float f; } v; v.u = ((unsigned)s) << 16; return v.f;
}

// async 16B global->LDS (per lane; LDS dest = wave-uniform base + lane*16)
__device__ inline void async_ld16(unsigned short* lds, const unsigned short* g) {
    __builtin_amdgcn_global_load_lds(
        (const __attribute__((address_space(1))) unsigned int*)(g),
        (__attribute__((address_space(3))) unsigned int*)(lds),
        16, 0, 0);
}

__device__ inline float block_sum256(float s, float* red) {
    for (int o = 32; o > 0; o >>= 1) s += __shfl_down(s, o, 64);
    int lane = threadIdx.x & 63, wid = threadIdx.x >> 6;
    if (lane == 0) red[wid] = s;
    __syncthreads();
    if (threadIdx.x == 0) red[4] = red[0] + red[1] + red[2] + red[3];
    __syncthreads();
    return red[4];
}

// ---------------------------------------------------------------------------
// Fused: blocks 0..255 transpose+convert the 4 weights to bf16;
// blocks 256..8447 do LN1 (x -> h bf16).
// ---------------------------------------------------------------------------
__global__ __launch_bounds__(256) void prep_kernel(const float* __restrict__ Wq,
                                                   const float* __restrict__ Wk,
                                                   const float* __restrict__ Wv,
                                                   const float* __restrict__ Wo,
                                                   unsigned short* __restrict__ WtAll,
                                                   const float* __restrict__ x,
                                                   const float* __restrict__ ln1_g,
                                                   const float* __restrict__ ln1_b,
                                                   unsigned short* __restrict__ h_bf) {
    __shared__ float red[8];
    const int bxg = blockIdx.x;
    if (bxg < 256) {
        int sub = bxg >> 6;
        const float* W = sub == 0 ? Wq : sub == 1 ? Wk : sub == 2 ? Wv : Wo;
        unsigned short* Wt = WtAll + (size_t)sub * 262144;
        int t = (bxg & 63) * 256 + threadIdx.x;
        int tn = t & 127, tk = t >> 7;
        int k = tk * 4, n = tn * 4;
        float4 r0 = *(const float4*)&W[(size_t)(k + 0) * 512 + n];
        float4 r1 = *(const float4*)&W[(size_t)(k + 1) * 512 + n];
        float4 r2 = *(const float4*)&W[(size_t)(k + 2) * 512 + n];
        float4 r3 = *(const float4*)&W[(size_t)(k + 3) * 512 + n];
        ushort4 c;
        c.x = bfbits(r0.x); c.y = bfbits(r1.x); c.z = bfbits(r2.x); c.w = bfbits(r3.x);
        *(ushort4*)&Wt[(size_t)(n + 0) * 512 + k] = c;
        c.x = bfbits(r0.y); c.y = bfbits(r1.y); c.z = bfbits(r2.y); c.w = bfbits(r3.y);
        *(ushort4*)&Wt[(size_t)(n + 1) * 512 + k] = c;
        c.x = bfbits(r0.z); c.y = bfbits(r1.z); c.z = bfbits(r2.z); c.w = bfbits(r3.z);
        *(ushort4*)&Wt[(size_t)(n + 2) * 512 + k] = c;
        c.x = bfbits(r0.w); c.y = bfbits(r1.w); c.z = bfbits(r2.w); c.w = bfbits(r3.w);
        *(ushort4*)&Wt[(size_t)(n + 3) * 512 + k] = c;
    } else {
        const int row = bxg - 256;
        const int t = threadIdx.x;
        const float* xr = x + (size_t)row * D;
        float v0 = xr[t], v1 = xr[t + 256];
        float mu = block_sum256(v0 + v1, red) * (1.0f / D);
        float d0 = v0 - mu, d1 = v1 - mu;
        float var = block_sum256(d0 * d0 + d1 * d1, red) * (1.0f / D);
        float rstd = rsqrtf(var + EPS_LN);
        h_bf[(size_t)row * D + t]       = bfbits(d0 * rstd * ln1_g[t] + ln1_b[t]);
        h_bf[(size_t)row * D + t + 256] = bfbits(d1 * rstd * ln1_g[t + 256] + ln1_b[t + 256]);
    }
}

// ---------------------------------------------------------------------------
// LN2: y = LN(bf16 Y0 + fp32 x) -> fp32 out
// ---------------------------------------------------------------------------
__global__ __launch_bounds__(256) void ln2_kernel(const unsigned short* __restrict__ y0,
                                                  const float* __restrict__ res,
                                                  const float* __restrict__ gamma,
                                                  const float* __restrict__ beta,
                                                  float* __restrict__ out) {
    __shared__ float red[8];
    const int row = blockIdx.x;
    const int t = threadIdx.x;
    const unsigned short* xr = y0 + (size_t)row * D;
    const float* rr = res + (size_t)row * D;
    float v0 = bf2f(xr[t]) + rr[t];
    float v1 = bf2f(xr[t + 256]) + rr[t + 256];
    float mu = block_sum256(v0 + v1, red) * (1.0f / D);
    float d0 = v0 - mu, d1 = v1 - mu;
    float var = block_sum256(d0 * d0 + d1 * d1, red) * (1.0f / D);
    float rstd = rsqrtf(var + EPS_LN);
    out[(size_t)row * D + t]       = d0 * rstd * gamma[t] + beta[t];
    out[(size_t)row * D + t + 256] = d1 * rstd * gamma[t + 256] + beta[t + 256];
}

// ---------------------------------------------------------------------------
// MTx128-tile bf16 MFMA GEMM, BK=64. A[M,512] @ Wt[n][k]. 1D grid, by=id&(RB-1)
// (XCD-local A reuse). MODE 0 (MT=64): bf16 out row-major.
// MODE 1 (MT=128): fused QKV epilogue (N=1536): Q,K -> [bh][n][dh] + sumsq,
// V -> [bh][dh][n] via LDS transpose.
// ---------------------------------------------------------------------------
template <int MODE, int MT>
__global__ __launch_bounds__(256) void gemm128(const unsigned short* __restrict__ A,
                                               const unsigned short* __restrict__ Wt,
                                               const float* __restrict__ bias0,
                                               const float* __restrict__ bias1,
                                               const float* __restrict__ bias2,
                                               void* __restrict__ o0,
                                               unsigned short* __restrict__ Ko,
                                               unsigned short* __restrict__ Vo,
                                               float* __restrict__ sq0,
                                               float* __restrict__ sq1) {
    constexpr int RB = M_ROWS / MT;
    constexpr int NI = MT / 32;
    constexpr int ASZ = MT * 64, BSZ = 128 * 64;
    constexpr int SMSZ = (MODE == 1) ? ((ASZ + BSZ > 18432) ? ASZ + BSZ : 18432)
                                     : (ASZ + BSZ);
    __shared__ unsigned short smem[SMSZ];
    unsigned short* As = smem;
    unsigned short* Bs = smem + ASZ;

    const int id = blockIdx.x;
    const int by = id & (RB - 1), bx = id / RB;
    const int tid = threadIdx.x;
    const int lane = tid & 63, wv = tid >> 6;
    const int quad = lane >> 4, l15 = lane & 15;
    const int row0 = by * MT, col0 = bx * 128;
    const int wm = (wv & 1) * (MT / 2), wn = (wv >> 1) * 64;

    f32x4 acc[NI][4];
    #pragma unroll
    for (int i = 0; i < NI; ++i)
        #pragma unroll
        for (int j = 0; j < 4; ++j) acc[i][j] = (f32x4){0.f, 0.f, 0.f, 0.f};

    const unsigned short* Ag = A  + (size_t)row0 * 512;
    const unsigned short* Bg = Wt + (size_t)col0 * 512;

    for (int k0 = 0; k0 < 512; k0 += 64) {
        __syncthreads();
        #pragma unroll
        for (int c = 0; c < ASZ / 2048; ++c) {
            int fu = c * 2048 + tid * 8;
            int r = fu >> 6, ko = fu & 63;
            async_ld16(As + fu, Ag + (size_t)r * 512 + k0 + ko);
        }
        #pragma unroll
        for (int c = 0; c < BSZ / 2048; ++c) {
            int fu = c * 2048 + tid * 8;
            int r = fu >> 6, ko = fu & 63;
            async_ld16(Bs + fu, Bg + (size_t)r * 512 + k0 + ko);
        }
        __syncthreads();

        #pragma unroll
        for (int ks = 0; ks < 2; ++ks) {
            short8 af[NI], bf[4];
            #pragma unroll
            for (int i = 0; i < NI; ++i)
                af[i] = *(const short8*)&As[(wm + i * 16 + l15) * 64 + ks * 32 + quad * 8];
            #pragma unroll
            for (int j = 0; j < 4; ++j)
                bf[j] = *(const short8*)&Bs[(wn + j * 16 + l15) * 64 + ks * 32 + quad * 8];
            #pragma unroll
            for (int i = 0; i < NI; ++i)
                #pragma unroll
                for (int j = 0; j < 4; ++j)
                    acc[i][j] = __builtin_amdgcn_mfma_f32_16x16x32_bf16(af[i], bf[j], acc[i][j], 0, 0, 0);
        }
    }

    if (MODE == 0) {
        unsigned short* C = (unsigned short*)o0;
        #pragma unroll
        for (int i = 0; i < NI; ++i)
            #pragma unroll
            for (int j = 0; j < 4; ++j) {
                int col = col0 + wn + j * 16 + l15;
                float bv = bias0[col];
                #pragma unroll
                for (int r = 0; r < 4; ++r) {
                    int row = row0 + wm + i * 16 + quad * 4 + r;
                    C[(size_t)row * 512 + col] = bfbits(acc[i][j][r] + bv);
                }
            }
    } else {
        const int colg = col0 + wn;
        const int seg = colg >> 9;                 // 0=Q 1=K 2=V
        const int hh = (colg & 511) >> 6;
        const float* bias = seg == 0 ? bias0 : seg == 1 ? bias1 : bias2;

        if (seg < 2) {
            unsigned short* dst = seg == 0 ? (unsigned short*)o0 : Ko;
            float* sq = seg == 0 ? sq0 : sq1;
            #pragma unroll
            for (int i = 0; i < NI; ++i) {
                const int m0 = row0 + wm + i * 16 + quad * 4;
                float ss[4] = {0.f, 0.f, 0.f, 0.f};
                #pragma unroll
                for (int j = 0; j < 4; ++j) {
                    float bvj = bias[hh * 64 + j * 16 + l15];
                    #pragma unroll
                    for (int r = 0; r < 4; ++r) {
                        float v = acc[i][j][r] + bvj;
                        unsigned short ub = bfbits(v);
                        float vr = bf2f(ub);
                        ss[r] += vr * vr;
                        int m = m0 + r;
                        int b_ = m >> 10, n_ = m & 1023;
                        dst[((size_t)((b_ * 8 + hh) * 1024) + n_) * 64 + j * 16 + l15] = ub;
                    }
                }
                #pragma unroll
                for (int r = 0; r < 4; ++r) {
                    float s = ss[r];
                    s += __shfl_xor(s, 1, 64);
                    s += __shfl_xor(s, 2, 64);
                    s += __shfl_xor(s, 4, 64);
                    s += __shfl_xor(s, 8, 64);
                    if (l15 == 0) {
                        int m = m0 + r;
                        sq[(size_t)((m >> 10) * 8 + hh) * 1024 + (m & 1023)] = s;
                    }
                }
            }
        } else {
            // V: transpose through per-wave LDS region, then coalesced stores
            __syncthreads();   // whole block is V (uniform): safe
            unsigned short* T = smem + wv * 4608;  // [64 d][72]
            #pragma unroll
            for (int i = 0; i < NI; ++i)
                #pragma unroll
                for (int j = 0; j < 4; ++j) {
                    float bvj = bias[hh * 64 + j * 16 + l15];
                    ushort4 pk;
                    pk.x = bfbits(acc[i][j][0] + bvj);
                    pk.y = bfbits(acc[i][j][1] + bvj);
                    pk.z = bfbits(acc[i][j][2] + bvj);
                    pk.w = bfbits(acc[i][j][3] + bvj);
                    *(ushort4*)&T[(j * 16 + l15) * 72 + i * 16 + quad * 4] = pk;
                }
            const int b_ = (row0 + wm) >> 10;
            const int nbase = (row0 + wm) & 1023;
            unsigned short* Vg = Vo + ((size_t)((b_ * 8 + hh) * 64)) * 1024 + nbase;
            #pragma unroll
            for (int it = 0; it < 8; ++it) {
                int dl = it * 8 + (lane >> 3);
                int nl = (lane & 7) * 8;
                uint4 v = *(const uint4*)&T[dl * 72 + nl];
                *(uint4*)&Vg[(size_t)dl * 1024 + nl] = v;
            }
        }
    }
}

// ---------------------------------------------------------------------------
// MFMA distance attention. Block = 8 waves (512 thr), 128 q rows (16 q/wave)
// per (b,h). V pre-transposed [bh][dh][n]. Double-buffered K/V + register
// prefetch; one barrier per key-tile. bh = id&63 -> same-head blocks same XCD.
// P stored via truncation (1 op); denominator from raw p.
// ---------------------------------------------------------------------------
__global__ __launch_bounds__(512) void attn_kernel(const unsigned short* __restrict__ Q,
                                                   const unsigned short* __restrict__ K,
                                                   const unsigned short* __restrict__ Vt,
                                                   const float* __restrict__ qsq,
                                                   const float* __restrict__ ksq,
                                                   unsigned short* __restrict__ O) {
    __shared__ unsigned short Ks[2][64][72];
    __shared__ unsigned short Vs[2][64][72];
    __shared__ unsigned short Ps[8][16][72];
    __shared__ float ksq_s[2][64];

    const int id = blockIdx.x;
    const int bh = id & 63, qb = id >> 6;
    const int q0 = qb * 128;
    const int tid = threadIdx.x;
    const int lane = tid & 63, w = tid >> 6;
    const int quad = lane >> 4, l15 = lane & 15;
    const int b_ = bh >> 3, h_ = bh & 7;

    const unsigned short* Qb = Q  + (size_t)bh * N * DH;
    const unsigned short* Kb = K  + (size_t)bh * N * DH;
    const unsigned short* Vb = Vt + (size_t)bh * DH * N;

    // Q fragments: rows q0 + w*16 + l15
    short8 qf0, qf1;
    {
        const unsigned short* qp = Qb + (size_t)(q0 + w * 16 + l15) * 64 + quad * 8;
        qf0 = *(const short8*)qp;
        qf1 = *(const short8*)(qp + 32);
    }
    float qe[4];
    #pragma unroll
    for (int r = 0; r < 4; ++r)
        qe[r] = qsq[bh * N + q0 + w * 16 + quad * 4 + r] + EPS_DIST;

    f32x4 oacc[4];
    #pragma unroll
    for (int dt = 0; dt < 4; ++dt) oacc[dt] = (f32x4){0.f, 0.f, 0.f, 0.f};
    float dpart[4] = {};

    // staging: 512 threads, 16B each -> one uint4 per K, one per V
    const int rr = tid >> 3, cc = (tid & 7) * 8;
    uint4 kreg, vreg;
    float ksreg = 0.f;

    kreg = *(const uint4*)(Kb + (size_t)rr * 64 + cc);
    vreg = *(const uint4*)(Vb + (size_t)rr * N + cc);
    if (tid < 64) ksreg = ksq[bh * N + tid];

    *(uint4*)&Ks[0][rr][cc] = kreg;
    *(uint4*)&Vs[0][rr][cc] = vreg;
    if (tid < 64) ksq_s[0][tid] = ksreg;
    __syncthreads();

    for (int kt = 0; kt < 16; ++kt) {
        const int cur = kt & 1;
        if (kt < 15) {
            kreg = *(const uint4*)(Kb + (size_t)((kt + 1) * 64 + rr) * 64 + cc);
            vreg = *(const uint4*)(Vb + (size_t)rr * N + (kt + 1) * 64 + cc);
            if (tid < 64) ksreg = ksq[bh * N + (kt + 1) * 64 + tid];
        }

        // scores + transform -> Ps  (16 q x 64 keys per wave)
        #pragma unroll
        for (int kb = 0; kb < 4; ++kb) {
            short8 kf0 = *(const short8*)&Ks[cur][kb * 16 + l15][quad * 8];
            short8 kf1 = *(const short8*)&Ks[cur][kb * 16 + l15][32 + quad * 8];
            float ks2 = ksq_s[cur][kb * 16 + l15];
            f32x4 sa = (f32x4){0.f, 0.f, 0.f, 0.f};
            sa = __builtin_amdgcn_mfma_f32_16x16x32_bf16(qf0, kf0, sa, 0, 0, 0);
            sa = __builtin_amdgcn_mfma_f32_16x16x32_bf16(qf1, kf1, sa, 0, 0, 0);
            #pragma unroll
            for (int r = 0; r < 4; ++r) {
                float d2 = fmaf(-2.0f, sa[r], qe[r] + ks2);
                d2 = fmaxf(d2, EPS_DIST);
                float p = __expf(-__builtin_amdgcn_sqrtf(d2));
                dpart[r] += p;
                union { float f; unsigned u; } pu; pu.f = p;
                Ps[w][quad * 4 + r][kb * 16 + l15] = (unsigned short)(pu.u >> 16);
            }
        }

        // PV
        short8 vf[4][2];
        #pragma unroll
        for (int dt = 0; dt < 4; ++dt)
            #pragma unroll
            for (int kc = 0; kc < 2; ++kc)
                vf[dt][kc] = *(const short8*)&Vs[cur][dt * 16 + l15][kc * 32 + quad * 8];
        #pragma unroll
        for (int kc = 0; kc < 2; ++kc) {
            short8 pf = *(const short8*)&Ps[w][l15][kc * 32 + quad * 8];
            #pragma unroll
            for (int dt = 0; dt < 4; ++dt)
                oacc[dt] = __builtin_amdgcn_mfma_f32_16x16x32_bf16(pf, vf[dt][kc], oacc[dt], 0, 0, 0);
        }

        if (kt < 15) {
            *(uint4*)&Ks[cur ^ 1][rr][cc] = kreg;
            *(uint4*)&Vs[cur ^ 1][rr][cc] = vreg;
            if (tid < 64) ksq_s[cur ^ 1][tid] = ksreg;
        }
        __syncthreads();
    }

    float rinv[4];
    #pragma unroll
    for (int r = 0; r < 4; ++r) {
        float s = dpart[r];
        s += __shfl_xor(s, 1, 64);
        s += __shfl_xor(s, 2, 64);
        s += __shfl_xor(s, 4, 64);
        s += __shfl_xor(s, 8, 64);
        rinv[r] = 1.0f / s;
    }

    #pragma unroll
    for (int dt = 0; dt < 4; ++dt)
        #pragma unroll
        for (int r = 0; r < 4; ++r) {
            int n_ = q0 + w * 16 + quad * 4 + r;
            O[((size_t)(b_ * N + n_) * D) + h_ * DH + dt * 16 + l15] =
                bfbits(oacc[dt][r] * rinv[r]);
        }
}

// ---------------------------------------------------------------------------
extern "C" void kernel_launch(void* const* d_in, const int* in_sizes, int n_in,
                              void* d_out, int out_size, void* d_ws, size_t ws_size,
                              hipStream_t stream) {
    const float* x     = (const float*)d_in[0];
    const float* Wq    = (const float*)d_in[1];
    const float* Wk    = (const float*)d_in[2];
    const float* Wv    = (const float*)d_in[3];
    const float* Wo    = (const float*)d_in[4];
    const float* bq    = (const float*)d_in[5];
    const float* bk    = (const float*)d_in[6];
    const float* bv    = (const float*)d_in[7];
    const float* bo    = (const float*)d_in[8];
    const float* ln1_g = (const float*)d_in[9];
    const float* ln1_b = (const float*)d_in[10];
    const float* ln2_g = (const float*)d_in[11];
    const float* ln2_b = (const float*)d_in[12];
    float* out = (float*)d_out;

    unsigned short* WtAll = (unsigned short*)d_ws;    // [4][512][512] bf16
    unsigned short* h_bf  = WtAll + 4 * 262144;       // [8192][512]
    unsigned short* Qb    = h_bf + 4194304;           // [64][1024][64]
    unsigned short* Kb    = Qb + 4194304;
    unsigned short* Vtg   = Kb + 4194304;             // [64][64][1024] transposed
    unsigned short* Ob    = Vtg + 4194304;            // [8192][512]
    unsigned short* Y0    = Ob + 4194304;             // [8192][512] bf16
    float* qsq = (float*)(Y0 + 4194304);              // [65536]
    float* ksq = qsq + 65536;

    // 1) weights -> bf16^T  +  LN1 -> bf16 (fused launch)
    prep_kernel<<<256 + M_ROWS, 256, 0, stream>>>(Wq, Wk, Wv, Wo, WtAll,
                                                  x, ln1_g, ln1_b, h_bf);

    // 2) fused QKV projection (N=1536) + scatter + sum-squares
    gemm128<1, 128><<<768, 256, 0, stream>>>(h_bf, WtAll, bq, bk, bv,
                                             Qb, Kb, Vtg, qsq, ksq);

    // 3) MFMA distance attention -> Ob [B,N,D] bf16
    attn_kernel<<<512, 512, 0, stream>>>(Qb, Kb, Vtg, qsq, ksq, Ob);

    // 4) output projection -> bf16 Y0
    gemm128<0, 64><<<512, 256, 0, stream>>>(Ob, WtAll + 3 * 262144, bo,
                                            nullptr, nullptr, Y0,
                                            nullptr, nullptr, nullptr, nullptr);

    // 5) residual + post-norm
    ln2_kernel<<<M_ROWS, 256, 0, stream>>>(Y0, x, ln2_g, ln2_b, out);
}